// Round 7
// baseline (664.056 us; speedup 1.0000x reference)
//
#include <hip/hip_runtime.h>
#include <hip/hip_bf16.h>
#include <math.h>

#define NNODES 100000
#define NEDGES 1600000
#define NB 782           // ceil(NNODES/128) buckets of 128 nodes
#define PB 256           // partition blocks (>= CU count)
#define EPB 6250         // NEDGES / PB exactly
#define SCAN_N (NB * PB) // 200192
#define SB ((SCAN_N + 1023) / 1024)  // 196 scan1 blocks
#define CAP 4608         // LDS stage capacity per bucket (avg 2048, max ~2300)
#define NCH 391          // ceil(NNODES/256) node chunks for aggslice

typedef __bf16 bf16x8 __attribute__((ext_vector_type(8)));
typedef float f32x4 __attribute__((ext_vector_type(4)));
typedef unsigned int u32x4 __attribute__((ext_vector_type(4)));

static __device__ inline unsigned short f2bf(float f) {
    __hip_bfloat16 h = __float2bfloat16(f);
    return *reinterpret_cast<unsigned short*>(&h);
}

// ---------------- pass A: per-block LDS histogram of dst>>7, fused with weight prep ----------------

static __device__ inline int packidx64(int k, int ch) {
    int s = k >> 5, r5 = k & 31, q = r5 >> 3, ii = r5 & 7;
    int t = ch >> 4, lo = ch & 15;
    int lane = q * 16 + lo;
    return ((t * 2 + s) * 64 + lane) * 8 + ii;
}

__global__ __launch_bounds__(256) void histprep_kernel(const int* __restrict__ dst,
                                                       int* __restrict__ histg,
                                                       const float* __restrict__ W1,
                                                       const float* __restrict__ W2,
                                                       const float* __restrict__ W3,
                                                       const float* __restrict__ W4,
                                                       const float* __restrict__ b3,
                                                       const float* __restrict__ b4,
                                                       unsigned short* __restrict__ Wp1,
                                                       unsigned short* __restrict__ Wp2,
                                                       unsigned short* __restrict__ Wp34,
                                                       float* __restrict__ b34,
                                                       unsigned short* __restrict__ hp) {
    __shared__ int h[NB];
    int tid = threadIdx.x, blk = blockIdx.x;
    if (blk < PB) {
        for (int b = tid; b < NB; b += 256) h[b] = 0;
        __syncthreads();
        int base = blk * EPB;
        for (int i = base + tid; i < base + EPB; i += 256)
            atomicAdd(&h[dst[i] >> 7], 1);
        __syncthreads();
        for (int b = tid; b < NB; b += 256) histg[b * PB + blk] = h[b];
        return;
    }
    int pb = blk - PB;
    if (pb < 32) {             // packW1, K=128, S=4
        int idx = pb * 256 + tid;
        int i = idx & 7, rest = idx >> 3;
        int lane = rest & 63; rest >>= 6;
        int s = rest % 4, t = rest / 4;
        int k = s * 32 + (lane >> 4) * 8 + i;
        int ch = t * 16 + (lane & 15);
        Wp1[idx] = f2bf(W1[k * 64 + ch]);
    } else if (pb < 48) {      // packW2, K=64, S=2
        int idx = (pb - 32) * 256 + tid;
        int i = idx & 7, rest = idx >> 3;
        int lane = rest & 63; rest >>= 6;
        int s = rest % 2, t = rest / 2;
        int k = s * 32 + (lane >> 4) * 8 + i;
        int ch = t * 16 + (lane & 15);
        Wp2[idx] = f2bf(W2[k * 64 + ch]);
    } else if (pb == 48) {     // zero pad row (legacy, harmless)
        if (tid < 64) hp[(size_t)NNODES * 64 + tid] = 0;
    } else if (pb < 65) {      // W34 = W3@W4 compute + pack
        int i = (pb - 49) * 4 + (tid >> 6);
        int j = tid & 63;
        float a = 0.f;
        for (int k = 0; k < 256; ++k) a = fmaf(W3[i * 256 + k], W4[k * 64 + j], a);
        Wp34[packidx64(i, j)] = f2bf(a);
    } else {                   // b34
        if (tid < 64) {
            int j = tid;
            float a = b4[j];
            for (int k = 0; k < 256; ++k) a = fmaf(b3[k], W4[k * 64 + j], a);
            b34[j] = a;
        }
    }
}

// ---------------- scan over SCAN_N elements (single dispatch; bsum scan done in consumers) ----------------

__global__ __launch_bounds__(256) void scan1_kernel(const int* __restrict__ cnt,
                                                    int* __restrict__ off,
                                                    int* __restrict__ bsum, int n) {
    __shared__ int tmp[256];
    int tid = threadIdx.x;
    int t4 = blockIdx.x * 1024 + tid * 4;
    int v0 = (t4 + 0 < n) ? cnt[t4 + 0] : 0;
    int v1 = (t4 + 1 < n) ? cnt[t4 + 1] : 0;
    int v2 = (t4 + 2 < n) ? cnt[t4 + 2] : 0;
    int v3 = (t4 + 3 < n) ? cnt[t4 + 3] : 0;
    int ssum = v0 + v1 + v2 + v3;
    tmp[tid] = ssum;
    __syncthreads();
    for (int d = 1; d < 256; d <<= 1) {
        int x = (tid >= d) ? tmp[tid - d] : 0;
        __syncthreads();
        tmp[tid] += x;
        __syncthreads();
    }
    int run = tmp[tid] - ssum;
    if (t4 + 0 < n) off[t4 + 0] = run; run += v0;
    if (t4 + 1 < n) off[t4 + 1] = run; run += v1;
    if (t4 + 2 < n) off[t4 + 2] = run; run += v2;
    if (t4 + 3 < n) off[t4 + 3] = run;
    if (tid == 255) bsum[blockIdx.x] = tmp[255];
}

// ---------------- pass B: partition via in-LDS counting sort (r4-proven form) ----------------

__global__ __launch_bounds__(256) void part_kernel(const int* __restrict__ src,
                                                   const int* __restrict__ dst,
                                                   const int* __restrict__ histg,
                                                   const int* __restrict__ gscan,
                                                   const int* __restrict__ bsum,
                                                   unsigned int* __restrict__ part) {
    __shared__ unsigned int sorted[EPB];
    __shared__ int gaddr[EPB];
    __shared__ int gcol[NB];
    __shared__ int base_l[NB];
    __shared__ int cur[NB];
    __shared__ int tmp[256];
    __shared__ int bse[256];
    int tid = threadIdx.x, blk = blockIdx.x;
    // block-sum exclusive scan (SB <= 256)
    int bv = (tid < SB) ? bsum[tid] : 0;
    tmp[tid] = bv;
    __syncthreads();
    for (int d = 1; d < 256; d <<= 1) {
        int x = (tid >= d) ? tmp[tid - d] : 0;
        __syncthreads();
        tmp[tid] += x;
        __syncthreads();
    }
    bse[tid] = tmp[tid] - bv;
    __syncthreads();
    // load this block's column: counts + global bases
    for (int b = tid; b < NB; b += 256) {
        int i = b * PB + blk;
        gcol[b] = gscan[i] + bse[i >> 10];
        base_l[b] = histg[i];  // counts, scanned in place below
        cur[b] = 0;
    }
    __syncthreads();
    // exclusive scan of base_l over NB (4 elements per thread)
    int t4 = tid * 4;
    int v0 = (t4 + 0 < NB) ? base_l[t4 + 0] : 0;
    int v1 = (t4 + 1 < NB) ? base_l[t4 + 1] : 0;
    int v2 = (t4 + 2 < NB) ? base_l[t4 + 2] : 0;
    int v3 = (t4 + 3 < NB) ? base_l[t4 + 3] : 0;
    int ssum = v0 + v1 + v2 + v3;
    tmp[tid] = ssum;
    __syncthreads();
    for (int d = 1; d < 256; d <<= 1) {
        int x = (tid >= d) ? tmp[tid - d] : 0;
        __syncthreads();
        tmp[tid] += x;
        __syncthreads();
    }
    int run = tmp[tid] - ssum;
    if (t4 + 0 < NB) base_l[t4 + 0] = run; run += v0;
    if (t4 + 1 < NB) base_l[t4 + 1] = run; run += v1;
    if (t4 + 2 < NB) base_l[t4 + 2] = run; run += v2;
    if (t4 + 3 < NB) base_l[t4 + 3] = run;
    __syncthreads();
    // place edges bucket-sorted into LDS
    int base = blk * EPB;
    for (int i = base + tid; i < base + EPB; i += 256) {
        int s = src[i], d = dst[i];
        int bkt = d >> 7;
        int r = atomicAdd(&cur[bkt], 1);
        int pos = base_l[bkt] + r;
        sorted[pos] = ((unsigned int)(d & 127) << 17) | (unsigned int)s;
        gaddr[pos] = gcol[bkt] + r;
    }
    __syncthreads();
    // linear flush: consecutive lanes -> mostly-consecutive global addresses
    for (int i = tid; i < EPB; i += 256)
        part[gaddr[i]] = sorted[i];
}

// ---------------- pass C: per-bucket CSR build + cnt/off/dinv, FUSED with gemm1 ----------------

__global__ __launch_bounds__(256) void csrgemm_kernel(const unsigned int* __restrict__ part,
                                                      const int* __restrict__ gscan,
                                                      const int* __restrict__ bsum,
                                                      const float* __restrict__ x,
                                                      const unsigned short* __restrict__ Wp1,
                                                      int* __restrict__ csr,
                                                      int* __restrict__ cnt_g,
                                                      int* __restrict__ off_g,
                                                      float* __restrict__ dinv_g,
                                                      unsigned short* __restrict__ hp, int n) {
    __shared__ unsigned int stage[CAP];
    __shared__ int hist2[128];
    __shared__ int sc[128];
    __shared__ int excl[128];
    __shared__ int cur2[128];
    __shared__ float sdinv[128];
    __shared__ int tmp[256];
    __shared__ int bse[256];
    int tid = threadIdx.x, b = blockIdx.x;
    // block-sum exclusive scan (SB <= 256)
    int bv = (tid < SB) ? bsum[tid] : 0;
    tmp[tid] = bv;
    __syncthreads();
    for (int d = 1; d < 256; d <<= 1) {
        int x2 = (tid >= d) ? tmp[tid - d] : 0;
        __syncthreads();
        tmp[tid] += x2;
        __syncthreads();
    }
    bse[tid] = tmp[tid] - bv;
    __syncthreads();
    int i0 = b * PB;
    int S = gscan[i0] + bse[i0 >> 10];
    int T = (b == NB - 1) ? NEDGES : (gscan[i0 + PB] + bse[(i0 + PB) >> 10]);
    int len = T - S;
    bool fit = (len <= CAP);
    if (tid < 128) { hist2[tid] = 0; cur2[tid] = 0; }
    __syncthreads();
    for (int i = tid; i < len; i += 256) {
        unsigned int p = part[S + i];
        if (fit) stage[i] = p;
        atomicAdd(&hist2[p >> 17], 1);
    }
    __syncthreads();
    if (tid < 128) sc[tid] = hist2[tid];
    __syncthreads();
    for (int d = 1; d < 128; d <<= 1) {
        int x2 = 0;
        if (tid < 128 && tid >= d) x2 = sc[tid - d];
        __syncthreads();
        if (tid < 128) sc[tid] += x2;
        __syncthreads();
    }
    if (tid < 128) {
        int c = hist2[tid];
        int ex = sc[tid] - c;
        excl[tid] = ex;
        float dv = rsqrtf((float)c + 1.0f);
        sdinv[tid] = dv;
        int node = b * 128 + tid;
        if (node < n) {
            cnt_g[node] = c;
            off_g[node] = S + ex;
            dinv_g[node] = dv;
        }
    }
    __syncthreads();
    for (int i = tid; i < len; i += 256) {
        unsigned int p = fit ? stage[i] : part[S + i];
        int dl = p >> 17;
        int s = (int)(p & 0x1FFFFu);
        int r = atomicAdd(&cur2[dl], 1);
        csr[S + excl[dl] + r] = s;   // plain src, sorted by dst-local
    }
    // ---- gemm1 phase: hp[node] = bf16( (x[node] @ W1) * dinv[node] ) for this bucket's nodes
    int wv = tid >> 6, lane = tid & 63;
    int q = lane >> 4, lo = lane & 15;
#pragma unroll
    for (int t2 = 0; t2 < 2; ++t2) {
        int nl0 = wv * 32 + t2 * 16;
        int nodeA = b * 128 + nl0 + lo;
        int na = nodeA < n ? nodeA : 0;
        f32x4 acc[4] = {};
#pragma unroll
        for (int s = 0; s < 4; ++s) {
            const float* xr = x + (size_t)na * 128 + q * 8 + s * 32;
            float4 u = *(const float4*)(xr);
            float4 v = *(const float4*)(xr + 4);
            bf16x8 a;
            a[0] = (__bf16)u.x; a[1] = (__bf16)u.y; a[2] = (__bf16)u.z; a[3] = (__bf16)u.w;
            a[4] = (__bf16)v.x; a[5] = (__bf16)v.y; a[6] = (__bf16)v.z; a[7] = (__bf16)v.w;
#pragma unroll
            for (int t = 0; t < 4; ++t) {
                bf16x8 bfr = *(const bf16x8*)(Wp1 + ((size_t)(t * 4 + s) * 64 + lane) * 8);
                acc[t] = __builtin_amdgcn_mfma_f32_16x16x32_bf16(a, bfr, acc[t], 0, 0, 0);
            }
        }
#pragma unroll
        for (int r = 0; r < 4; ++r) {
            int nl = nl0 + q * 4 + r;
            int node = b * 128 + nl;
            if (node < n) {
                float di = sdinv[nl];
#pragma unroll
                for (int t = 0; t < 4; ++t)
                    hp[(size_t)node * 64 + t * 16 + lo] = f2bf(acc[t][r] * di);
            }
        }
    }
}

// ---------------- channel-sliced aggregation, XCD-pinned ----------------
// Block bid: node chunk = bid>>3, channel slice = bid&7 (8 channels = 16B of
// each 128B row). Blocks with equal bid&7 land on the same XCD (round-robin
// dispatch), so each XCD's gather working set is 100000*16B = 1.6MB -> L2-
// resident. One thread per node, serial edge loop, 2-deep pipelined 16B loads,
// register accumulation. Epilogue: out = bf16(relu(acc*dinv + bias_slice)).

__global__ __launch_bounds__(256) void aggslice_kernel(const unsigned short* __restrict__ hsrc,
                                                       const int* __restrict__ csr,
                                                       const int* __restrict__ off,
                                                       const int* __restrict__ cnt,
                                                       const float* __restrict__ dinv,
                                                       const float* __restrict__ bias,
                                                       unsigned short* __restrict__ out, int n) {
    int bid = blockIdx.x;
    int chunk = bid >> 3, slice8 = (bid & 7) * 8;
    int node = chunk * 256 + threadIdx.x;
    if (node >= n) return;
    const unsigned short* tab = hsrc + slice8;

    int c = cnt[node];
    int s = off[node];
    const int* cp = csr + s;

    float accA[8];
    float accB[8] = {};
    // self-loop init (hsrc rows are pre-scaled by dinv[src])
    {
        u32x4 su = *(const u32x4*)(tab + (size_t)node * 64);
#pragma unroll
        for (int k = 0; k < 4; ++k) {
            accA[2 * k]     = __builtin_bit_cast(float, su[k] << 16);
            accA[2 * k + 1] = __builtin_bit_cast(float, su[k] & 0xFFFF0000u);
        }
    }
    int s0 = 0, s1 = 0;
    if (c > 0) s0 = cp[0];
    if (c > 1) s1 = cp[1];
    int j = 0;
    for (; j + 2 <= c; j += 2) {
        u32x4 ua = *(const u32x4*)(tab + (size_t)s0 * 64);
        u32x4 ub = *(const u32x4*)(tab + (size_t)s1 * 64);
        if (j + 3 < c)      { s0 = cp[j + 2]; s1 = cp[j + 3]; }
        else if (j + 2 < c) { s0 = cp[j + 2]; }
#pragma unroll
        for (int k = 0; k < 4; ++k) {
            accA[2 * k]     += __builtin_bit_cast(float, ua[k] << 16);
            accA[2 * k + 1] += __builtin_bit_cast(float, ua[k] & 0xFFFF0000u);
            accB[2 * k]     += __builtin_bit_cast(float, ub[k] << 16);
            accB[2 * k + 1] += __builtin_bit_cast(float, ub[k] & 0xFFFF0000u);
        }
    }
    if (j < c) {  // odd tail; s0 holds cp[c-1]
        u32x4 ua = *(const u32x4*)(tab + (size_t)s0 * 64);
#pragma unroll
        for (int k = 0; k < 4; ++k) {
            accA[2 * k]     += __builtin_bit_cast(float, ua[k] << 16);
            accA[2 * k + 1] += __builtin_bit_cast(float, ua[k] & 0xFFFF0000u);
        }
    }

    float di = dinv[node];
    float4 bv0 = *(const float4*)(bias + slice8);
    float4 bv1 = *(const float4*)(bias + slice8 + 4);
    float bb[8] = {bv0.x, bv0.y, bv0.z, bv0.w, bv1.x, bv1.y, bv1.z, bv1.w};
    unsigned short ov[8];
#pragma unroll
    for (int k = 0; k < 8; ++k)
        ov[k] = f2bf(fmaxf(fmaf(accA[k] + accB[k], di, bb[k]), 0.f));
    *(ushort4*)(out + (size_t)node * 64 + slice8)     = make_ushort4(ov[0], ov[1], ov[2], ov[3]);
    *(ushort4*)(out + (size_t)node * 64 + slice8 + 4) = make_ushort4(ov[4], ov[5], ov[6], ov[7]);
}

// ---------------- MFMA GEMM: K=64, out[N,64] = X[N,64] @ W[64,64] ----------------
// !LSM: out = bf16((X@W)*dinv)  (pre-scaled input for the next aggregation)
// LSM:  out = log_softmax(X@W + biasB)

template <bool LSM>
__global__ __launch_bounds__(256) void gemm64_kernel(const unsigned short* __restrict__ Xb,
                                                     const unsigned short* __restrict__ Wp,
                                                     const float* __restrict__ biasB,
                                                     const float* __restrict__ dinv,
                                                     unsigned short* __restrict__ outb,
                                                     float* __restrict__ outf, int n) {
    int w = threadIdx.x >> 6, lane = threadIdx.x & 63;
    int q = lane >> 4, lo = lane & 15;
    int base = blockIdx.x * 64 + w * 16;
    int nodeA = base + lo;
    int na = nodeA < n ? nodeA : 0;

    f32x4 acc[4] = {};
#pragma unroll
    for (int s = 0; s < 2; ++s) {
        bf16x8 a = *(const bf16x8*)(Xb + (size_t)na * 64 + q * 8 + s * 32);
#pragma unroll
        for (int t = 0; t < 4; ++t) {
            bf16x8 b = *(const bf16x8*)(Wp + ((size_t)(t * 2 + s) * 64 + lane) * 8);
            acc[t] = __builtin_amdgcn_mfma_f32_16x16x32_bf16(a, b, acc[t], 0, 0, 0);
        }
    }

    if (!LSM) {
#pragma unroll
        for (int r = 0; r < 4; ++r) {
            int node = base + q * 4 + r;
            if (node < n) {
                float di = dinv[node];
#pragma unroll
                for (int t = 0; t < 4; ++t)
                    outb[(size_t)node * 64 + t * 16 + lo] = f2bf(acc[t][r] * di);
            }
        }
    } else {
#pragma unroll
        for (int r = 0; r < 4; ++r) {
            int node = base + q * 4 + r;
            float v0 = acc[0][r] + biasB[0 * 16 + lo];
            float v1 = acc[1][r] + biasB[1 * 16 + lo];
            float v2 = acc[2][r] + biasB[2 * 16 + lo];
            float v3 = acc[3][r] + biasB[3 * 16 + lo];
            float mx = fmaxf(fmaxf(v0, v1), fmaxf(v2, v3));
            for (int d = 1; d < 16; d <<= 1) mx = fmaxf(mx, __shfl_xor(mx, d));
            float sm = __expf(v0 - mx) + __expf(v1 - mx) + __expf(v2 - mx) + __expf(v3 - mx);
            for (int d = 1; d < 16; d <<= 1) sm += __shfl_xor(sm, d);
            float lse = mx + __logf(sm);
            if (node < n) {
                outf[(size_t)node * 64 + 0 * 16 + lo] = v0 - lse;
                outf[(size_t)node * 64 + 1 * 16 + lo] = v1 - lse;
                outf[(size_t)node * 64 + 2 * 16 + lo] = v2 - lse;
                outf[(size_t)node * 64 + 3 * 16 + lo] = v3 - lse;
            }
        }
    }
}

// ---------------- launch ----------------

extern "C" void kernel_launch(void* const* d_in, const int* in_sizes, int n_in,
                              void* d_out, int out_size, void* d_ws, size_t ws_size,
                              hipStream_t stream) {
    const float* x  = (const float*)d_in[0];
    const int*   ei = (const int*)d_in[1];   // int32 (JAX x64 disabled demotes int64)
    const float* W1 = (const float*)d_in[2];
    const float* b1 = (const float*)d_in[3];
    const float* W2 = (const float*)d_in[4];
    const float* b2 = (const float*)d_in[5];
    const float* W3 = (const float*)d_in[6];
    const float* b3 = (const float*)d_in[7];
    const float* W4 = (const float*)d_in[8];
    const float* b4 = (const float*)d_in[9];
    float* outp = (float*)d_out;

    const int N = NNODES;
    const int E = NEDGES;
    const int* srcp = ei;
    const int* dstp = ei + E;

    char* w = (char*)d_ws;
    size_t o = 0;
    auto alloc = [&](size_t bytes) { size_t r = o; o = (o + bytes + 255) & ~(size_t)255; return r; };
    size_t cnt_off   = alloc((size_t)N * 4);
    size_t off_off   = alloc((size_t)N * 4);
    size_t dinv_off  = alloc((size_t)N * 4);
    size_t histg_off = alloc((size_t)SCAN_N * 4);
    size_t gscan_off = alloc((size_t)SCAN_N * 4);
    size_t bs_off    = alloc(256 * 4);
    size_t part_off  = alloc((size_t)E * 4);
    size_t csr_off   = alloc((size_t)E * 4);
    size_t hp_off    = alloc((size_t)(N + 1) * 64 * 2);  // +1 zeroed pad row
    size_t abf_off   = alloc((size_t)N * 64 * 2);
    size_t wp1_off   = alloc(128 * 64 * 2);
    size_t wp2_off   = alloc(64 * 64 * 2);
    size_t wp34_off  = alloc(64 * 64 * 2);
    size_t b34_off   = alloc(64 * 4);

    int*            cnt   = (int*)(w + cnt_off);
    int*            off   = (int*)(w + off_off);
    float*          dinv  = (float*)(w + dinv_off);
    int*            histg = (int*)(w + histg_off);
    int*            gscan = (int*)(w + gscan_off);
    int*            bs    = (int*)(w + bs_off);
    unsigned int*   part  = (unsigned int*)(w + part_off);
    int*            csr   = (int*)(w + csr_off);
    unsigned short* hp    = (unsigned short*)(w + hp_off);
    unsigned short* abf   = (unsigned short*)(w + abf_off);
    unsigned short* Wp1   = (unsigned short*)(w + wp1_off);
    unsigned short* Wp2   = (unsigned short*)(w + wp2_off);
    unsigned short* Wp34  = (unsigned short*)(w + wp34_off);
    float*          b34   = (float*)(w + b34_off);

    histprep_kernel<<<PB + 66, 256, 0, stream>>>(dstp, histg, W1, W2, W3, W4, b3, b4,
                                                 Wp1, Wp2, Wp34, b34, hp);
    scan1_kernel<<<SB, 256, 0, stream>>>(histg, gscan, bs, SCAN_N);
    part_kernel<<<PB, 256, 0, stream>>>(srcp, dstp, histg, gscan, bs, part);
    csrgemm_kernel<<<NB, 256, 0, stream>>>(part, gscan, bs, x, Wp1, csr, cnt, off, dinv, hp, N);

    const int ag = NCH * 8;               // 3128 blocks: chunk*8 + slice
    const int gb = (N + 63) / 64;         // 1563

    // layer 1: h1 = relu(agg(hp)*dinv + b1); hp2 = (h1@W2)*dinv
    aggslice_kernel<<<ag, 256, 0, stream>>>(hp, csr, off, cnt, dinv, b1, abf, N);
    gemm64_kernel<false><<<gb, 256, 0, stream>>>(abf, Wp2, nullptr, dinv, hp, nullptr, N);
    // layer 2: h2 = relu(agg(hp)*dinv + b2); out = log_softmax(h2@W34 + b34)
    aggslice_kernel<<<ag, 256, 0, stream>>>(hp, csr, off, cnt, dinv, b2, abf, N);
    gemm64_kernel<true><<<gb, 256, 0, stream>>>(abf, Wp34, b34, nullptr, nullptr, outp, N);
}

// Round 8
// 264.496 us; speedup vs baseline: 2.5106x; 2.5106x over previous
//
#include <hip/hip_runtime.h>
#include <hip/hip_bf16.h>
#include <math.h>

#define NNODES 100000
#define NEDGES 1600000
#define NB 782           // ceil(NNODES/128) buckets of 128 nodes
#define PB 256           // partition blocks (>= CU count)
#define EPB 6250         // NEDGES / PB exactly
#define SCAN_N (NB * PB) // 200192
#define SB ((SCAN_N + 1023) / 1024)  // 196 scan1 blocks
#define CAP 4608         // LDS stage capacity per bucket (avg 2048, max ~2300)
#define HTS 72           // LDS h-tile row stride in bf16 (144B -> bank-rotating, 2-way max)
#define ANB 64           // nodes per aggfuse block (grid 1563)
#define DBINS 64         // degree bins for counting sort (clamp at 63)

typedef __bf16 bf16x8 __attribute__((ext_vector_type(8)));
typedef float f32x4 __attribute__((ext_vector_type(4)));
typedef unsigned int u32x4 __attribute__((ext_vector_type(4)));
typedef unsigned short u16x8 __attribute__((ext_vector_type(8)));

static __device__ inline unsigned short f2bf(float f) {
    __hip_bfloat16 h = __float2bfloat16(f);
    return *reinterpret_cast<unsigned short*>(&h);
}

// ---------------- pass A: per-block LDS histogram of dst>>7, fused with weight prep ----------------

static __device__ inline int packidx64(int k, int ch) {
    int s = k >> 5, r5 = k & 31, q = r5 >> 3, ii = r5 & 7;
    int t = ch >> 4, lo = ch & 15;
    int lane = q * 16 + lo;
    return ((t * 2 + s) * 64 + lane) * 8 + ii;
}

__global__ __launch_bounds__(256) void histprep_kernel(const int* __restrict__ dst,
                                                       int* __restrict__ histg,
                                                       const float* __restrict__ W1,
                                                       const float* __restrict__ W2,
                                                       const float* __restrict__ W3,
                                                       const float* __restrict__ W4,
                                                       const float* __restrict__ b3,
                                                       const float* __restrict__ b4,
                                                       unsigned short* __restrict__ Wp1,
                                                       unsigned short* __restrict__ Wp2,
                                                       unsigned short* __restrict__ Wp34,
                                                       float* __restrict__ b34,
                                                       unsigned short* __restrict__ hp,
                                                       int* __restrict__ dhist,
                                                       int* __restrict__ gcur) {
    __shared__ int h[NB];
    int tid = threadIdx.x, blk = blockIdx.x;
    if (blk < PB) {
        for (int b = tid; b < NB; b += 256) h[b] = 0;
        __syncthreads();
        int base = blk * EPB;
        for (int i = base + tid; i < base + EPB; i += 256)
            atomicAdd(&h[dst[i] >> 7], 1);
        __syncthreads();
        for (int b = tid; b < NB; b += 256) histg[b * PB + blk] = h[b];
        return;
    }
    int pb = blk - PB;
    if (pb < 32) {             // packW1, K=128, S=4
        int idx = pb * 256 + tid;
        int i = idx & 7, rest = idx >> 3;
        int lane = rest & 63; rest >>= 6;
        int s = rest % 4, t = rest / 4;
        int k = s * 32 + (lane >> 4) * 8 + i;
        int ch = t * 16 + (lane & 15);
        Wp1[idx] = f2bf(W1[k * 64 + ch]);
    } else if (pb < 48) {      // packW2, K=64, S=2
        int idx = (pb - 32) * 256 + tid;
        int i = idx & 7, rest = idx >> 3;
        int lane = rest & 63; rest >>= 6;
        int s = rest % 2, t = rest / 2;
        int k = s * 32 + (lane >> 4) * 8 + i;
        int ch = t * 16 + (lane & 15);
        Wp2[idx] = f2bf(W2[k * 64 + ch]);
    } else if (pb == 48) {     // zero pad row + degree-sort scratch
        if (tid < 64) hp[(size_t)NNODES * 64 + tid] = 0;
        if (tid < DBINS) { dhist[tid] = 0; gcur[tid] = 0; }
    } else if (pb < 65) {      // W34 = W3@W4 compute + pack
        int i = (pb - 49) * 4 + (tid >> 6);
        int j = tid & 63;
        float a = 0.f;
        for (int k = 0; k < 256; ++k) a = fmaf(W3[i * 256 + k], W4[k * 64 + j], a);
        Wp34[packidx64(i, j)] = f2bf(a);
    } else {                   // b34
        if (tid < 64) {
            int j = tid;
            float a = b4[j];
            for (int k = 0; k < 256; ++k) a = fmaf(b3[k], W4[k * 64 + j], a);
            b34[j] = a;
        }
    }
}

// ---------------- scan over SCAN_N elements (single dispatch; bsum scan done in consumers) ----------------

__global__ __launch_bounds__(256) void scan1_kernel(const int* __restrict__ cnt,
                                                    int* __restrict__ off,
                                                    int* __restrict__ bsum, int n) {
    __shared__ int tmp[256];
    int tid = threadIdx.x;
    int t4 = blockIdx.x * 1024 + tid * 4;
    int v0 = (t4 + 0 < n) ? cnt[t4 + 0] : 0;
    int v1 = (t4 + 1 < n) ? cnt[t4 + 1] : 0;
    int v2 = (t4 + 2 < n) ? cnt[t4 + 2] : 0;
    int v3 = (t4 + 3 < n) ? cnt[t4 + 3] : 0;
    int ssum = v0 + v1 + v2 + v3;
    tmp[tid] = ssum;
    __syncthreads();
    for (int d = 1; d < 256; d <<= 1) {
        int x = (tid >= d) ? tmp[tid - d] : 0;
        __syncthreads();
        tmp[tid] += x;
        __syncthreads();
    }
    int run = tmp[tid] - ssum;
    if (t4 + 0 < n) off[t4 + 0] = run; run += v0;
    if (t4 + 1 < n) off[t4 + 1] = run; run += v1;
    if (t4 + 2 < n) off[t4 + 2] = run; run += v2;
    if (t4 + 3 < n) off[t4 + 3] = run;
    if (tid == 255) bsum[blockIdx.x] = tmp[255];
}

// ---------------- pass B: partition via in-LDS counting sort ----------------
// gaddr int array replaced by ushort bucket ids (flush recomputes the address
// from base_l/gcol): LDS 57->49 KB, 2->3 blocks/CU.

__global__ __launch_bounds__(256) void part_kernel(const int* __restrict__ src,
                                                   const int* __restrict__ dst,
                                                   const int* __restrict__ histg,
                                                   const int* __restrict__ gscan,
                                                   const int* __restrict__ bsum,
                                                   unsigned int* __restrict__ part) {
    __shared__ unsigned int sorted[EPB];
    __shared__ unsigned short bktb[EPB];
    __shared__ int gcol[NB];
    __shared__ int base_l[NB];
    __shared__ int cur[NB];
    __shared__ int tmp[256];
    __shared__ int bse[256];
    int tid = threadIdx.x, blk = blockIdx.x;
    // block-sum exclusive scan (SB <= 256)
    int bv = (tid < SB) ? bsum[tid] : 0;
    tmp[tid] = bv;
    __syncthreads();
    for (int d = 1; d < 256; d <<= 1) {
        int x = (tid >= d) ? tmp[tid - d] : 0;
        __syncthreads();
        tmp[tid] += x;
        __syncthreads();
    }
    bse[tid] = tmp[tid] - bv;
    __syncthreads();
    // load this block's column: counts + global bases
    for (int b = tid; b < NB; b += 256) {
        int i = b * PB + blk;
        gcol[b] = gscan[i] + bse[i >> 10];
        base_l[b] = histg[i];  // counts, scanned in place below
        cur[b] = 0;
    }
    __syncthreads();
    // exclusive scan of base_l over NB (4 elements per thread)
    int t4 = tid * 4;
    int v0 = (t4 + 0 < NB) ? base_l[t4 + 0] : 0;
    int v1 = (t4 + 1 < NB) ? base_l[t4 + 1] : 0;
    int v2 = (t4 + 2 < NB) ? base_l[t4 + 2] : 0;
    int v3 = (t4 + 3 < NB) ? base_l[t4 + 3] : 0;
    int ssum = v0 + v1 + v2 + v3;
    tmp[tid] = ssum;
    __syncthreads();
    for (int d = 1; d < 256; d <<= 1) {
        int x = (tid >= d) ? tmp[tid - d] : 0;
        __syncthreads();
        tmp[tid] += x;
        __syncthreads();
    }
    int run = tmp[tid] - ssum;
    if (t4 + 0 < NB) base_l[t4 + 0] = run; run += v0;
    if (t4 + 1 < NB) base_l[t4 + 1] = run; run += v1;
    if (t4 + 2 < NB) base_l[t4 + 2] = run; run += v2;
    if (t4 + 3 < NB) base_l[t4 + 3] = run;
    __syncthreads();
    // place edges bucket-sorted into LDS
    int base = blk * EPB;
    for (int i = base + tid; i < base + EPB; i += 256) {
        int s = src[i], d = dst[i];
        int bkt = d >> 7;
        int r = atomicAdd(&cur[bkt], 1);
        int pos = base_l[bkt] + r;
        sorted[pos] = ((unsigned int)(d & 127) << 17) | (unsigned int)s;
        bktb[pos] = (unsigned short)bkt;
    }
    __syncthreads();
    // linear flush: consecutive lanes -> mostly-consecutive global addresses
    for (int i = tid; i < EPB; i += 256) {
        int bkt = bktb[i];
        part[gcol[bkt] + (i - base_l[bkt])] = sorted[i];
    }
}

// ---------------- pass C: per-bucket CSR build + cnt/off/dinv + degree hist, FUSED with gemm1 ----------------

__global__ __launch_bounds__(256) void csrgemm_kernel(const unsigned int* __restrict__ part,
                                                      const int* __restrict__ gscan,
                                                      const int* __restrict__ bsum,
                                                      const float* __restrict__ x,
                                                      const unsigned short* __restrict__ Wp1,
                                                      int* __restrict__ csr,
                                                      int* __restrict__ cnt_g,
                                                      int* __restrict__ off_g,
                                                      float* __restrict__ dinv_g,
                                                      unsigned short* __restrict__ hp,
                                                      int* __restrict__ dhist, int n) {
    __shared__ unsigned int stage[CAP];
    __shared__ int hist2[128];
    __shared__ int sc[128];
    __shared__ int excl[128];
    __shared__ int cur2[128];
    __shared__ float sdinv[128];
    __shared__ int tmp[256];
    __shared__ int bse[256];
    __shared__ int dh[DBINS];
    int tid = threadIdx.x, b = blockIdx.x;
    // block-sum exclusive scan (SB <= 256)
    int bv = (tid < SB) ? bsum[tid] : 0;
    tmp[tid] = bv;
    __syncthreads();
    for (int d = 1; d < 256; d <<= 1) {
        int x2 = (tid >= d) ? tmp[tid - d] : 0;
        __syncthreads();
        tmp[tid] += x2;
        __syncthreads();
    }
    bse[tid] = tmp[tid] - bv;
    __syncthreads();
    int i0 = b * PB;
    int S = gscan[i0] + bse[i0 >> 10];
    int T = (b == NB - 1) ? NEDGES : (gscan[i0 + PB] + bse[(i0 + PB) >> 10]);
    int len = T - S;
    bool fit = (len <= CAP);
    if (tid < 128) { hist2[tid] = 0; cur2[tid] = 0; }
    if (tid < DBINS) dh[tid] = 0;
    __syncthreads();
    for (int i = tid; i < len; i += 256) {
        unsigned int p = part[S + i];
        if (fit) stage[i] = p;
        atomicAdd(&hist2[p >> 17], 1);
    }
    __syncthreads();
    if (tid < 128) sc[tid] = hist2[tid];
    __syncthreads();
    for (int d = 1; d < 128; d <<= 1) {
        int x2 = 0;
        if (tid < 128 && tid >= d) x2 = sc[tid - d];
        __syncthreads();
        if (tid < 128) sc[tid] += x2;
        __syncthreads();
    }
    if (tid < 128) {
        int c = hist2[tid];
        int ex = sc[tid] - c;
        excl[tid] = ex;
        float dv = rsqrtf((float)c + 1.0f);
        sdinv[tid] = dv;
        int node = b * 128 + tid;
        if (node < n) {
            cnt_g[node] = c;
            off_g[node] = S + ex;
            dinv_g[node] = dv;
            atomicAdd(&dh[c < 63 ? c : 63], 1);
        }
    }
    __syncthreads();
    if (tid < DBINS && dh[tid] > 0) atomicAdd(&dhist[tid], dh[tid]);
    for (int i = tid; i < len; i += 256) {
        unsigned int p = fit ? stage[i] : part[S + i];
        int dl = p >> 17;
        int s = (int)(p & 0x1FFFFu);
        int r = atomicAdd(&cur2[dl], 1);
        csr[S + excl[dl] + r] = s;   // plain src, sorted by dst-local
    }
    // ---- gemm1 phase: hp[node] = bf16( (x[node] @ W1) * dinv[node] ) for this bucket's nodes
    int wv = tid >> 6, lane = tid & 63;
    int q = lane >> 4, lo = lane & 15;
#pragma unroll
    for (int t2 = 0; t2 < 2; ++t2) {
        int nl0 = wv * 32 + t2 * 16;
        int nodeA = b * 128 + nl0 + lo;
        int na = nodeA < n ? nodeA : 0;
        f32x4 acc[4] = {};
#pragma unroll
        for (int s = 0; s < 4; ++s) {
            const float* xr = x + (size_t)na * 128 + q * 8 + s * 32;
            float4 u = *(const float4*)(xr);
            float4 v = *(const float4*)(xr + 4);
            bf16x8 a;
            a[0] = (__bf16)u.x; a[1] = (__bf16)u.y; a[2] = (__bf16)u.z; a[3] = (__bf16)u.w;
            a[4] = (__bf16)v.x; a[5] = (__bf16)v.y; a[6] = (__bf16)v.z; a[7] = (__bf16)v.w;
#pragma unroll
            for (int t = 0; t < 4; ++t) {
                bf16x8 bfr = *(const bf16x8*)(Wp1 + ((size_t)(t * 4 + s) * 64 + lane) * 8);
                acc[t] = __builtin_amdgcn_mfma_f32_16x16x32_bf16(a, bfr, acc[t], 0, 0, 0);
            }
        }
#pragma unroll
        for (int r = 0; r < 4; ++r) {
            int nl = nl0 + q * 4 + r;
            int node = b * 128 + nl;
            if (node < n) {
                float di = sdinv[nl];
#pragma unroll
                for (int t = 0; t < 4; ++t)
                    hp[(size_t)node * 64 + t * 16 + lo] = f2bf(acc[t][r] * di);
            }
        }
    }
}

// ---------------- degree-sort permutation (counting sort, two-level atomics) ----------------
// perm[rank] = node, ranks grouped by degree bin. Waves in aggfuse then process
// similar-degree nodes together -> max ~= mean -> no barrier tail.

__global__ __launch_bounds__(256) void permute_kernel(const int* __restrict__ cnt,
                                                      const int* __restrict__ dhist,
                                                      int* __restrict__ gcur,
                                                      int* __restrict__ perm, int n) {
    __shared__ int dbase[DBINS];
    __shared__ int lh[DBINS];
    __shared__ int lbase[DBINS];
    __shared__ int lcur[DBINS];
    __shared__ int sc[DBINS];
    int tid = threadIdx.x;
    int node = blockIdx.x * 256 + tid;
    // global exclusive scan of dhist (64 entries)
    if (tid < DBINS) { sc[tid] = dhist[tid]; lh[tid] = 0; lcur[tid] = 0; }
    __syncthreads();
    for (int d = 1; d < DBINS; d <<= 1) {
        int v = 0;
        if (tid < DBINS && tid >= d) v = sc[tid - d];
        __syncthreads();
        if (tid < DBINS) sc[tid] += v;
        __syncthreads();
    }
    if (tid < DBINS) dbase[tid] = sc[tid] - dhist[tid];
    __syncthreads();
    int bin = -1;
    if (node < n) {
        int c = cnt[node];
        bin = c < 63 ? c : 63;
        atomicAdd(&lh[bin], 1);
    }
    __syncthreads();
    if (tid < DBINS && lh[tid] > 0) lbase[tid] = atomicAdd(&gcur[tid], lh[tid]);
    __syncthreads();
    if (node < n) {
        int r = atomicAdd(&lcur[bin], 1);
        perm[dbase[bin] + lbase[bin] + r] = node;
    }
}

// ---------------- fused aggregate + GEMM (degree-sorted) ----------------
// One block per 64 perm slots. 32 groups x 8 lanes; each group owns 2 nodes
// (via perm), register accumulation (coalesced 128B gathers, bf16->f32
// shift/mask). 4-deep pipelined. h = relu(agg*dinv+biasA) staged to padded
// LDS, then each of the 4 waves runs the K=64 MFMA for one 16-row tile;
// outputs scatter through the stored node ids.

template <bool LSM>
__global__ __launch_bounds__(256) void aggfuse_kernel(const unsigned short* __restrict__ hsrc,
                                                      const int* __restrict__ csr,
                                                      const int* __restrict__ off,
                                                      const int* __restrict__ cnt,
                                                      const float* __restrict__ dinv,
                                                      const float* __restrict__ biasA,
                                                      const unsigned short* __restrict__ Wp,
                                                      const float* __restrict__ biasB,
                                                      const int* __restrict__ perm,
                                                      unsigned short* __restrict__ outb,
                                                      float* __restrict__ outf, int n) {
    __shared__ __align__(16) unsigned short ht[ANB * HTS];
    __shared__ int pnode[ANB];
    int tid = threadIdx.x, b = blockIdx.x;
    int g = tid >> 3, cl = tid & 7, c8 = cl * 8;
    float4 bv0 = *(const float4*)(biasA + c8);
    float4 bv1 = *(const float4*)(biasA + c8 + 4);
    float bb[8] = {bv0.x, bv0.y, bv0.z, bv0.w, bv1.x, bv1.y, bv1.z, bv1.w};
#pragma unroll 1
    for (int i = 0; i < 2; ++i) {
        int nl = g * 2 + i;
        int slot = b * ANB + nl;
        int node = (slot < n) ? perm[slot] : -1;
        if (cl == 0) pnode[nl] = node;
        u16x8 hv;
#pragma unroll
        for (int k = 0; k < 8; ++k) hv[k] = 0;
        if (node >= 0) {
            int s = off[node];
            int c = cnt[node];
            const int* cp = csr + s;
            float acc0[8];
            float acc1[8] = {};
            // init acc0 with the self-loop row (hsrc rows are pre-scaled by dinv[src])
            bf16x8 sv = *(const bf16x8*)(hsrc + (size_t)node * 64 + c8);
            u32x4 su = __builtin_bit_cast(u32x4, sv);
#pragma unroll
            for (int k = 0; k < 4; ++k) {
                acc0[2 * k]     = __builtin_bit_cast(float, su[k] << 16);
                acc0[2 * k + 1] = __builtin_bit_cast(float, su[k] & 0xFFFF0000u);
            }
            int n0 = 0, n1 = 0, n2 = 0, n3 = 0;
            if (c >= 4) { n0 = cp[0]; n1 = cp[1]; n2 = cp[2]; n3 = cp[3]; }
            int j = 0;
            for (; j + 4 <= c; j += 4) {
                bf16x8 va = *(const bf16x8*)(hsrc + (size_t)n0 * 64 + c8);
                bf16x8 vb = *(const bf16x8*)(hsrc + (size_t)n1 * 64 + c8);
                bf16x8 vc = *(const bf16x8*)(hsrc + (size_t)n2 * 64 + c8);
                bf16x8 vd = *(const bf16x8*)(hsrc + (size_t)n3 * 64 + c8);
                int jn = j + 4;
                if (jn + 4 <= c) { n0 = cp[jn]; n1 = cp[jn + 1]; n2 = cp[jn + 2]; n3 = cp[jn + 3]; }
                u32x4 ua = __builtin_bit_cast(u32x4, va);
                u32x4 ub = __builtin_bit_cast(u32x4, vb);
                u32x4 uc = __builtin_bit_cast(u32x4, vc);
                u32x4 ud = __builtin_bit_cast(u32x4, vd);
#pragma unroll
                for (int k = 0; k < 4; ++k) {
                    acc0[2 * k]     += __builtin_bit_cast(float, ua[k] << 16);
                    acc0[2 * k + 1] += __builtin_bit_cast(float, ua[k] & 0xFFFF0000u);
                    acc1[2 * k]     += __builtin_bit_cast(float, ub[k] << 16);
                    acc1[2 * k + 1] += __builtin_bit_cast(float, ub[k] & 0xFFFF0000u);
                    acc0[2 * k]     += __builtin_bit_cast(float, uc[k] << 16);
                    acc0[2 * k + 1] += __builtin_bit_cast(float, uc[k] & 0xFFFF0000u);
                    acc1[2 * k]     += __builtin_bit_cast(float, ud[k] << 16);
                    acc1[2 * k + 1] += __builtin_bit_cast(float, ud[k] & 0xFFFF0000u);
                }
            }
            for (; j < c; ++j) {   // tail 0..3 edges
                int nt = cp[j];
                bf16x8 va = *(const bf16x8*)(hsrc + (size_t)nt * 64 + c8);
                u32x4 ua = __builtin_bit_cast(u32x4, va);
#pragma unroll
                for (int k = 0; k < 4; ++k) {
                    acc0[2 * k]     += __builtin_bit_cast(float, ua[k] << 16);
                    acc0[2 * k + 1] += __builtin_bit_cast(float, ua[k] & 0xFFFF0000u);
                }
            }
            float di = dinv[node];
#pragma unroll
            for (int k = 0; k < 8; ++k)
                hv[k] = f2bf(fmaxf(fmaf(acc0[k] + acc1[k], di, bb[k]), 0.f));
        }
        *(u16x8*)(&ht[nl * HTS + c8]) = hv;
    }
    __syncthreads();
    // ---- MFMA phase: wave wv handles one 16-row tile, K=64 (S=2)
    int wv = tid >> 6, lane = tid & 63;
    int q = lane >> 4, lo = lane & 15;
    int nl0 = wv * 16;
    f32x4 acc[4] = {};
#pragma unroll
    for (int s = 0; s < 2; ++s) {
        bf16x8 a = *(const bf16x8*)(&ht[(nl0 + lo) * HTS + s * 32 + q * 8]);
#pragma unroll
        for (int t = 0; t < 4; ++t) {
            bf16x8 bfr = *(const bf16x8*)(Wp + ((size_t)(t * 2 + s) * 64 + lane) * 8);
            acc[t] = __builtin_amdgcn_mfma_f32_16x16x32_bf16(a, bfr, acc[t], 0, 0, 0);
        }
    }
    if (!LSM) {
#pragma unroll
        for (int r = 0; r < 4; ++r) {
            int node = pnode[nl0 + q * 4 + r];
            if (node >= 0) {
                float di = dinv[node];
#pragma unroll
                for (int t = 0; t < 4; ++t)
                    outb[(size_t)node * 64 + t * 16 + lo] = f2bf(acc[t][r] * di);
            }
        }
    } else {
#pragma unroll
        for (int r = 0; r < 4; ++r) {
            int node = pnode[nl0 + q * 4 + r];
            float v0 = acc[0][r] + biasB[0 * 16 + lo];
            float v1 = acc[1][r] + biasB[1 * 16 + lo];
            float v2 = acc[2][r] + biasB[2 * 16 + lo];
            float v3 = acc[3][r] + biasB[3 * 16 + lo];
            float mx = fmaxf(fmaxf(v0, v1), fmaxf(v2, v3));
            for (int d = 1; d < 16; d <<= 1) mx = fmaxf(mx, __shfl_xor(mx, d));
            float sm = __expf(v0 - mx) + __expf(v1 - mx) + __expf(v2 - mx) + __expf(v3 - mx);
            for (int d = 1; d < 16; d <<= 1) sm += __shfl_xor(sm, d);
            float lse = mx + __logf(sm);
            if (node >= 0) {
                outf[(size_t)node * 64 + 0 * 16 + lo] = v0 - lse;
                outf[(size_t)node * 64 + 1 * 16 + lo] = v1 - lse;
                outf[(size_t)node * 64 + 2 * 16 + lo] = v2 - lse;
                outf[(size_t)node * 64 + 3 * 16 + lo] = v3 - lse;
            }
        }
    }
}

// ---------------- launch ----------------

extern "C" void kernel_launch(void* const* d_in, const int* in_sizes, int n_in,
                              void* d_out, int out_size, void* d_ws, size_t ws_size,
                              hipStream_t stream) {
    const float* x  = (const float*)d_in[0];
    const int*   ei = (const int*)d_in[1];   // int32 (JAX x64 disabled demotes int64)
    const float* W1 = (const float*)d_in[2];
    const float* b1 = (const float*)d_in[3];
    const float* W2 = (const float*)d_in[4];
    const float* b2 = (const float*)d_in[5];
    const float* W3 = (const float*)d_in[6];
    const float* b3 = (const float*)d_in[7];
    const float* W4 = (const float*)d_in[8];
    const float* b4 = (const float*)d_in[9];
    float* outp = (float*)d_out;

    const int N = NNODES;
    const int E = NEDGES;
    const int* srcp = ei;
    const int* dstp = ei + E;

    char* w = (char*)d_ws;
    size_t o = 0;
    auto alloc = [&](size_t bytes) { size_t r = o; o = (o + bytes + 255) & ~(size_t)255; return r; };
    size_t cnt_off   = alloc((size_t)N * 4);
    size_t off_off   = alloc((size_t)N * 4);
    size_t dinv_off  = alloc((size_t)N * 4);
    size_t perm_off  = alloc((size_t)N * 4);
    size_t histg_off = alloc((size_t)SCAN_N * 4);
    size_t gscan_off = alloc((size_t)SCAN_N * 4);
    size_t bs_off    = alloc(256 * 4);
    size_t dh_off    = alloc(DBINS * 4);
    size_t gc_off    = alloc(DBINS * 4);
    size_t part_off  = alloc((size_t)E * 4);
    size_t csr_off   = alloc((size_t)E * 4);
    size_t hp_off    = alloc((size_t)(N + 1) * 64 * 2);  // +1 zeroed pad row
    size_t abf_off   = alloc((size_t)N * 64 * 2);
    size_t wp1_off   = alloc(128 * 64 * 2);
    size_t wp2_off   = alloc(64 * 64 * 2);
    size_t wp34_off  = alloc(64 * 64 * 2);
    size_t b34_off   = alloc(64 * 4);

    int*            cnt   = (int*)(w + cnt_off);
    int*            off   = (int*)(w + off_off);
    float*          dinv  = (float*)(w + dinv_off);
    int*            perm  = (int*)(w + perm_off);
    int*            histg = (int*)(w + histg_off);
    int*            gscan = (int*)(w + gscan_off);
    int*            bs    = (int*)(w + bs_off);
    int*            dhist = (int*)(w + dh_off);
    int*            gcur  = (int*)(w + gc_off);
    unsigned int*   part  = (unsigned int*)(w + part_off);
    int*            csr   = (int*)(w + csr_off);
    unsigned short* hp    = (unsigned short*)(w + hp_off);
    unsigned short* abf   = (unsigned short*)(w + abf_off);
    unsigned short* Wp1   = (unsigned short*)(w + wp1_off);
    unsigned short* Wp2   = (unsigned short*)(w + wp2_off);
    unsigned short* Wp34  = (unsigned short*)(w + wp34_off);
    float*          b34   = (float*)(w + b34_off);

    histprep_kernel<<<PB + 66, 256, 0, stream>>>(dstp, histg, W1, W2, W3, W4, b3, b4,
                                                 Wp1, Wp2, Wp34, b34, hp, dhist, gcur);
    scan1_kernel<<<SB, 256, 0, stream>>>(histg, gscan, bs, SCAN_N);
    part_kernel<<<PB, 256, 0, stream>>>(srcp, dstp, histg, gscan, bs, part);
    csrgemm_kernel<<<NB, 256, 0, stream>>>(part, gscan, bs, x, Wp1, csr, cnt, off, dinv, hp, dhist, N);

    const int pg = (N + 255) / 256;       // 391
    permute_kernel<<<pg, 256, 0, stream>>>(cnt, dhist, gcur, perm, N);

    const int ab = (N + ANB - 1) / ANB;   // 1563

    aggfuse_kernel<false><<<ab, 256, 0, stream>>>(hp, csr, off, cnt, dinv, b1, Wp2,
                                                  nullptr, perm, abf, nullptr, N);
    aggfuse_kernel<true><<<ab, 256, 0, stream>>>(abf, csr, off, cnt, dinv, b2, Wp34,
                                                 b34, perm, nullptr, outp, N);
}

// Round 9
// 243.813 us; speedup vs baseline: 2.7236x; 1.0848x over previous
//
#include <hip/hip_runtime.h>
#include <hip/hip_bf16.h>
#include <math.h>

#define NNODES 100000
#define NEDGES 1600000
#define NB 782           // ceil(NNODES/128) buckets of 128 nodes
#define PB 256           // partition blocks (>= CU count)
#define EPB 6250         // NEDGES / PB exactly
#define SCAN_N (NB * PB) // 200192
#define SB ((SCAN_N + 1023) / 1024)  // 196 scan1 blocks
#define CAP 4608         // LDS stage capacity per bucket (avg 2048, max ~2300)
#define HTS 72           // LDS h-tile row stride in bf16 (144B -> bank-rotating, 2-way max)
#define ANB 64           // nodes per aggfuse block (grid 1563)

typedef __bf16 bf16x8 __attribute__((ext_vector_type(8)));
typedef float f32x4 __attribute__((ext_vector_type(4)));
typedef unsigned int u32x4 __attribute__((ext_vector_type(4)));
typedef unsigned short u16x8 __attribute__((ext_vector_type(8)));

static __device__ inline unsigned short f2bf(float f) {
    __hip_bfloat16 h = __float2bfloat16(f);
    return *reinterpret_cast<unsigned short*>(&h);
}

// ---------------- pass A: per-block LDS histogram of dst>>7, fused with weight prep ----------------

static __device__ inline int packidx64(int k, int ch) {
    int s = k >> 5, r5 = k & 31, q = r5 >> 3, ii = r5 & 7;
    int t = ch >> 4, lo = ch & 15;
    int lane = q * 16 + lo;
    return ((t * 2 + s) * 64 + lane) * 8 + ii;
}

__global__ __launch_bounds__(256) void histprep_kernel(const int* __restrict__ dst,
                                                       int* __restrict__ histg,
                                                       const float* __restrict__ W1,
                                                       const float* __restrict__ W2,
                                                       const float* __restrict__ W3,
                                                       const float* __restrict__ W4,
                                                       const float* __restrict__ b3,
                                                       const float* __restrict__ b4,
                                                       unsigned short* __restrict__ Wp1,
                                                       unsigned short* __restrict__ Wp2,
                                                       unsigned short* __restrict__ Wp34,
                                                       float* __restrict__ b34,
                                                       unsigned short* __restrict__ hp) {
    __shared__ int h[NB];
    int tid = threadIdx.x, blk = blockIdx.x;
    if (blk < PB) {
        for (int b = tid; b < NB; b += 256) h[b] = 0;
        __syncthreads();
        int base = blk * EPB;
        for (int i = base + tid; i < base + EPB; i += 256)
            atomicAdd(&h[dst[i] >> 7], 1);
        __syncthreads();
        for (int b = tid; b < NB; b += 256) histg[b * PB + blk] = h[b];
        return;
    }
    int pb = blk - PB;
    if (pb < 32) {             // packW1, K=128, S=4
        int idx = pb * 256 + tid;
        int i = idx & 7, rest = idx >> 3;
        int lane = rest & 63; rest >>= 6;
        int s = rest % 4, t = rest / 4;
        int k = s * 32 + (lane >> 4) * 8 + i;
        int ch = t * 16 + (lane & 15);
        Wp1[idx] = f2bf(W1[k * 64 + ch]);
    } else if (pb < 48) {      // packW2, K=64, S=2
        int idx = (pb - 32) * 256 + tid;
        int i = idx & 7, rest = idx >> 3;
        int lane = rest & 63; rest >>= 6;
        int s = rest % 2, t = rest / 2;
        int k = s * 32 + (lane >> 4) * 8 + i;
        int ch = t * 16 + (lane & 15);
        Wp2[idx] = f2bf(W2[k * 64 + ch]);
    } else if (pb == 48) {     // zero pad row (legacy, harmless)
        if (tid < 64) hp[(size_t)NNODES * 64 + tid] = 0;
    } else if (pb < 65) {      // W34 = W3@W4 compute + pack
        int i = (pb - 49) * 4 + (tid >> 6);
        int j = tid & 63;
        float a = 0.f;
        for (int k = 0; k < 256; ++k) a = fmaf(W3[i * 256 + k], W4[k * 64 + j], a);
        Wp34[packidx64(i, j)] = f2bf(a);
    } else {                   // b34
        if (tid < 64) {
            int j = tid;
            float a = b4[j];
            for (int k = 0; k < 256; ++k) a = fmaf(b3[k], W4[k * 64 + j], a);
            b34[j] = a;
        }
    }
}

// ---------------- scan over SCAN_N elements (single dispatch; bsum scan done in consumers) ----------------

__global__ __launch_bounds__(256) void scan1_kernel(const int* __restrict__ cnt,
                                                    int* __restrict__ off,
                                                    int* __restrict__ bsum, int n) {
    __shared__ int tmp[256];
    int tid = threadIdx.x;
    int t4 = blockIdx.x * 1024 + tid * 4;
    int v0 = (t4 + 0 < n) ? cnt[t4 + 0] : 0;
    int v1 = (t4 + 1 < n) ? cnt[t4 + 1] : 0;
    int v2 = (t4 + 2 < n) ? cnt[t4 + 2] : 0;
    int v3 = (t4 + 3 < n) ? cnt[t4 + 3] : 0;
    int ssum = v0 + v1 + v2 + v3;
    tmp[tid] = ssum;
    __syncthreads();
    for (int d = 1; d < 256; d <<= 1) {
        int x = (tid >= d) ? tmp[tid - d] : 0;
        __syncthreads();
        tmp[tid] += x;
        __syncthreads();
    }
    int run = tmp[tid] - ssum;
    if (t4 + 0 < n) off[t4 + 0] = run; run += v0;
    if (t4 + 1 < n) off[t4 + 1] = run; run += v1;
    if (t4 + 2 < n) off[t4 + 2] = run; run += v2;
    if (t4 + 3 < n) off[t4 + 3] = run;
    if (tid == 255) bsum[blockIdx.x] = tmp[255];
}

// ---------------- pass B: partition via in-LDS counting sort ----------------
// ushort bucket ids instead of int gaddr (flush recomputes address): ~49KB LDS.

__global__ __launch_bounds__(256) void part_kernel(const int* __restrict__ src,
                                                   const int* __restrict__ dst,
                                                   const int* __restrict__ histg,
                                                   const int* __restrict__ gscan,
                                                   const int* __restrict__ bsum,
                                                   unsigned int* __restrict__ part) {
    __shared__ unsigned int sorted[EPB];
    __shared__ unsigned short bktb[EPB];
    __shared__ int gcol[NB];
    __shared__ int base_l[NB];
    __shared__ int cur[NB];
    __shared__ int tmp[256];
    __shared__ int bse[256];
    int tid = threadIdx.x, blk = blockIdx.x;
    // block-sum exclusive scan (SB <= 256)
    int bv = (tid < SB) ? bsum[tid] : 0;
    tmp[tid] = bv;
    __syncthreads();
    for (int d = 1; d < 256; d <<= 1) {
        int x = (tid >= d) ? tmp[tid - d] : 0;
        __syncthreads();
        tmp[tid] += x;
        __syncthreads();
    }
    bse[tid] = tmp[tid] - bv;
    __syncthreads();
    // load this block's column: counts + global bases
    for (int b = tid; b < NB; b += 256) {
        int i = b * PB + blk;
        gcol[b] = gscan[i] + bse[i >> 10];
        base_l[b] = histg[i];  // counts, scanned in place below
        cur[b] = 0;
    }
    __syncthreads();
    // exclusive scan of base_l over NB (4 elements per thread)
    int t4 = tid * 4;
    int v0 = (t4 + 0 < NB) ? base_l[t4 + 0] : 0;
    int v1 = (t4 + 1 < NB) ? base_l[t4 + 1] : 0;
    int v2 = (t4 + 2 < NB) ? base_l[t4 + 2] : 0;
    int v3 = (t4 + 3 < NB) ? base_l[t4 + 3] : 0;
    int ssum = v0 + v1 + v2 + v3;
    tmp[tid] = ssum;
    __syncthreads();
    for (int d = 1; d < 256; d <<= 1) {
        int x = (tid >= d) ? tmp[tid - d] : 0;
        __syncthreads();
        tmp[tid] += x;
        __syncthreads();
    }
    int run = tmp[tid] - ssum;
    if (t4 + 0 < NB) base_l[t4 + 0] = run; run += v0;
    if (t4 + 1 < NB) base_l[t4 + 1] = run; run += v1;
    if (t4 + 2 < NB) base_l[t4 + 2] = run; run += v2;
    if (t4 + 3 < NB) base_l[t4 + 3] = run;
    __syncthreads();
    // place edges bucket-sorted into LDS
    int base = blk * EPB;
    for (int i = base + tid; i < base + EPB; i += 256) {
        int s = src[i], d = dst[i];
        int bkt = d >> 7;
        int r = atomicAdd(&cur[bkt], 1);
        int pos = base_l[bkt] + r;
        sorted[pos] = ((unsigned int)(d & 127) << 17) | (unsigned int)s;
        bktb[pos] = (unsigned short)bkt;
    }
    __syncthreads();
    // linear flush: consecutive lanes -> mostly-consecutive global addresses
    for (int i = tid; i < EPB; i += 256) {
        int bkt = bktb[i];
        part[gcol[bkt] + (i - base_l[bkt])] = sorted[i];
    }
}

// ---------------- pass C: per-bucket CSR build + cnt/off/dinv, FUSED with gemm1 ----------------

__global__ __launch_bounds__(256) void csrgemm_kernel(const unsigned int* __restrict__ part,
                                                      const int* __restrict__ gscan,
                                                      const int* __restrict__ bsum,
                                                      const float* __restrict__ x,
                                                      const unsigned short* __restrict__ Wp1,
                                                      int* __restrict__ csr,
                                                      int* __restrict__ cnt_g,
                                                      int* __restrict__ off_g,
                                                      float* __restrict__ dinv_g,
                                                      unsigned short* __restrict__ hp, int n) {
    __shared__ unsigned int stage[CAP];
    __shared__ int hist2[128];
    __shared__ int sc[128];
    __shared__ int excl[128];
    __shared__ int cur2[128];
    __shared__ float sdinv[128];
    __shared__ int tmp[256];
    __shared__ int bse[256];
    int tid = threadIdx.x, b = blockIdx.x;
    // block-sum exclusive scan (SB <= 256)
    int bv = (tid < SB) ? bsum[tid] : 0;
    tmp[tid] = bv;
    __syncthreads();
    for (int d = 1; d < 256; d <<= 1) {
        int x2 = (tid >= d) ? tmp[tid - d] : 0;
        __syncthreads();
        tmp[tid] += x2;
        __syncthreads();
    }
    bse[tid] = tmp[tid] - bv;
    __syncthreads();
    int i0 = b * PB;
    int S = gscan[i0] + bse[i0 >> 10];
    int T = (b == NB - 1) ? NEDGES : (gscan[i0 + PB] + bse[(i0 + PB) >> 10]);
    int len = T - S;
    bool fit = (len <= CAP);
    if (tid < 128) { hist2[tid] = 0; cur2[tid] = 0; }
    __syncthreads();
    for (int i = tid; i < len; i += 256) {
        unsigned int p = part[S + i];
        if (fit) stage[i] = p;
        atomicAdd(&hist2[p >> 17], 1);
    }
    __syncthreads();
    if (tid < 128) sc[tid] = hist2[tid];
    __syncthreads();
    for (int d = 1; d < 128; d <<= 1) {
        int x2 = 0;
        if (tid < 128 && tid >= d) x2 = sc[tid - d];
        __syncthreads();
        if (tid < 128) sc[tid] += x2;
        __syncthreads();
    }
    if (tid < 128) {
        int c = hist2[tid];
        int ex = sc[tid] - c;
        excl[tid] = ex;
        float dv = rsqrtf((float)c + 1.0f);
        sdinv[tid] = dv;
        int node = b * 128 + tid;
        if (node < n) {
            cnt_g[node] = c;
            off_g[node] = S + ex;
            dinv_g[node] = dv;
        }
    }
    __syncthreads();
    for (int i = tid; i < len; i += 256) {
        unsigned int p = fit ? stage[i] : part[S + i];
        int dl = p >> 17;
        int s = (int)(p & 0x1FFFFu);
        int r = atomicAdd(&cur2[dl], 1);
        csr[S + excl[dl] + r] = s;   // plain src, sorted by dst-local
    }
    // ---- gemm1 phase: hp[node] = bf16( (x[node] @ W1) * dinv[node] ) for this bucket's nodes
    int wv = tid >> 6, lane = tid & 63;
    int q = lane >> 4, lo = lane & 15;
#pragma unroll
    for (int t2 = 0; t2 < 2; ++t2) {
        int nl0 = wv * 32 + t2 * 16;
        int nodeA = b * 128 + nl0 + lo;
        int na = nodeA < n ? nodeA : 0;
        f32x4 acc[4] = {};
#pragma unroll
        for (int s = 0; s < 4; ++s) {
            const float* xr = x + (size_t)na * 128 + q * 8 + s * 32;
            float4 u = *(const float4*)(xr);
            float4 v = *(const float4*)(xr + 4);
            bf16x8 a;
            a[0] = (__bf16)u.x; a[1] = (__bf16)u.y; a[2] = (__bf16)u.z; a[3] = (__bf16)u.w;
            a[4] = (__bf16)v.x; a[5] = (__bf16)v.y; a[6] = (__bf16)v.z; a[7] = (__bf16)v.w;
#pragma unroll
            for (int t = 0; t < 4; ++t) {
                bf16x8 bfr = *(const bf16x8*)(Wp1 + ((size_t)(t * 4 + s) * 64 + lane) * 8);
                acc[t] = __builtin_amdgcn_mfma_f32_16x16x32_bf16(a, bfr, acc[t], 0, 0, 0);
            }
        }
#pragma unroll
        for (int r = 0; r < 4; ++r) {
            int nl = nl0 + q * 4 + r;
            int node = b * 128 + nl;
            if (node < n) {
                float di = sdinv[nl];
#pragma unroll
                for (int t = 0; t < 4; ++t)
                    hp[(size_t)node * 64 + t * 16 + lo] = f2bf(acc[t][r] * di);
            }
        }
    }
}

// ---------------- fused aggregate + GEMM with LOCAL degree pairing ----------------
// One block per 64 nodes. Degrees of the block's 64 nodes are ranked in LDS;
// group g processes the rank-g and rank-(63-g) nodes, so every group's combined
// degree ~= 2*mean -> no barrier tail (r8's GLOBAL sort broke CSR locality;
// this local pairing keeps all reads in the same 64-node window). ht rows are
// written at the node's original local index, so the MFMA phase is unchanged.

template <bool LSM>
__global__ __launch_bounds__(256) void aggfuse_kernel(const unsigned short* __restrict__ hsrc,
                                                      const int* __restrict__ csr,
                                                      const int* __restrict__ off,
                                                      const int* __restrict__ cnt,
                                                      const float* __restrict__ dinv,
                                                      const float* __restrict__ biasA,
                                                      const unsigned short* __restrict__ Wp,
                                                      const float* __restrict__ biasB,
                                                      unsigned short* __restrict__ outb,
                                                      float* __restrict__ outf, int n) {
    __shared__ __align__(16) unsigned short ht[ANB * HTS];
    __shared__ int sdeg[ANB];
    __shared__ unsigned char sord[ANB];
    int tid = threadIdx.x, b = blockIdx.x;
    int g = tid >> 3, cl = tid & 7, c8 = cl * 8;
    // rank the block's 64 nodes by degree (desc); pad nodes (deg -1) sort last
    if (tid < ANB) {
        int node = b * ANB + tid;
        sdeg[tid] = (node < n) ? cnt[node] : -1;
    }
    __syncthreads();
    if (tid < ANB) {
        int d = sdeg[tid];
        int r = 0;
#pragma unroll 8
        for (int j = 0; j < ANB; ++j) {
            int dj = sdeg[j];
            r += (dj > d) || (dj == d && j < tid);
        }
        sord[r] = (unsigned char)tid;
    }
    __syncthreads();
    float4 bv0 = *(const float4*)(biasA + c8);
    float4 bv1 = *(const float4*)(biasA + c8 + 4);
    float bb[8] = {bv0.x, bv0.y, bv0.z, bv0.w, bv1.x, bv1.y, bv1.z, bv1.w};
#pragma unroll 1
    for (int i = 0; i < 2; ++i) {
        int nl = sord[i == 0 ? g : (ANB - 1 - g)];
        int node = b * ANB + nl;
        u16x8 hv;
#pragma unroll
        for (int k = 0; k < 8; ++k) hv[k] = 0;
        if (node < n) {
            int s = off[node];
            int c = cnt[node];
            const int* cp = csr + s;
            float acc0[8];
            float acc1[8] = {};
            // init acc0 with the self-loop row (hsrc rows are pre-scaled by dinv[src])
            bf16x8 sv = *(const bf16x8*)(hsrc + (size_t)node * 64 + c8);
            u32x4 su = __builtin_bit_cast(u32x4, sv);
#pragma unroll
            for (int k = 0; k < 4; ++k) {
                acc0[2 * k]     = __builtin_bit_cast(float, su[k] << 16);
                acc0[2 * k + 1] = __builtin_bit_cast(float, su[k] & 0xFFFF0000u);
            }
            int n0 = 0, n1 = 0, n2 = 0, n3 = 0;
            if (c >= 4) { n0 = cp[0]; n1 = cp[1]; n2 = cp[2]; n3 = cp[3]; }
            int j = 0;
            for (; j + 4 <= c; j += 4) {
                bf16x8 va = *(const bf16x8*)(hsrc + (size_t)n0 * 64 + c8);
                bf16x8 vb = *(const bf16x8*)(hsrc + (size_t)n1 * 64 + c8);
                bf16x8 vc = *(const bf16x8*)(hsrc + (size_t)n2 * 64 + c8);
                bf16x8 vd = *(const bf16x8*)(hsrc + (size_t)n3 * 64 + c8);
                int jn = j + 4;
                if (jn + 4 <= c) { n0 = cp[jn]; n1 = cp[jn + 1]; n2 = cp[jn + 2]; n3 = cp[jn + 3]; }
                u32x4 ua = __builtin_bit_cast(u32x4, va);
                u32x4 ub = __builtin_bit_cast(u32x4, vb);
                u32x4 uc = __builtin_bit_cast(u32x4, vc);
                u32x4 ud = __builtin_bit_cast(u32x4, vd);
#pragma unroll
                for (int k = 0; k < 4; ++k) {
                    acc0[2 * k]     += __builtin_bit_cast(float, ua[k] << 16);
                    acc0[2 * k + 1] += __builtin_bit_cast(float, ua[k] & 0xFFFF0000u);
                    acc1[2 * k]     += __builtin_bit_cast(float, ub[k] << 16);
                    acc1[2 * k + 1] += __builtin_bit_cast(float, ub[k] & 0xFFFF0000u);
                    acc0[2 * k]     += __builtin_bit_cast(float, uc[k] << 16);
                    acc0[2 * k + 1] += __builtin_bit_cast(float, uc[k] & 0xFFFF0000u);
                    acc1[2 * k]     += __builtin_bit_cast(float, ud[k] << 16);
                    acc1[2 * k + 1] += __builtin_bit_cast(float, ud[k] & 0xFFFF0000u);
                }
            }
            for (; j < c; ++j) {   // tail 0..3 edges
                int nt = cp[j];
                bf16x8 va = *(const bf16x8*)(hsrc + (size_t)nt * 64 + c8);
                u32x4 ua = __builtin_bit_cast(u32x4, va);
#pragma unroll
                for (int k = 0; k < 4; ++k) {
                    acc0[2 * k]     += __builtin_bit_cast(float, ua[k] << 16);
                    acc0[2 * k + 1] += __builtin_bit_cast(float, ua[k] & 0xFFFF0000u);
                }
            }
            float di = dinv[node];
#pragma unroll
            for (int k = 0; k < 8; ++k)
                hv[k] = f2bf(fmaxf(fmaf(acc0[k] + acc1[k], di, bb[k]), 0.f));
        }
        *(u16x8*)(&ht[nl * HTS + c8]) = hv;
    }
    __syncthreads();
    // ---- MFMA phase: wave wv handles one 16-node tile, K=64 (S=2)
    int wv = tid >> 6, lane = tid & 63;
    int q = lane >> 4, lo = lane & 15;
    int nl0 = wv * 16;
    f32x4 acc[4] = {};
#pragma unroll
    for (int s = 0; s < 2; ++s) {
        bf16x8 a = *(const bf16x8*)(&ht[(nl0 + lo) * HTS + s * 32 + q * 8]);
#pragma unroll
        for (int t = 0; t < 4; ++t) {
            bf16x8 bfr = *(const bf16x8*)(Wp + ((size_t)(t * 2 + s) * 64 + lane) * 8);
            acc[t] = __builtin_amdgcn_mfma_f32_16x16x32_bf16(a, bfr, acc[t], 0, 0, 0);
        }
    }
    if (!LSM) {
#pragma unroll
        for (int r = 0; r < 4; ++r) {
            int node = b * ANB + nl0 + q * 4 + r;
            if (node < n) {
                float di = dinv[node];
#pragma unroll
                for (int t = 0; t < 4; ++t)
                    outb[(size_t)node * 64 + t * 16 + lo] = f2bf(acc[t][r] * di);
            }
        }
    } else {
#pragma unroll
        for (int r = 0; r < 4; ++r) {
            int node = b * ANB + nl0 + q * 4 + r;
            float v0 = acc[0][r] + biasB[0 * 16 + lo];
            float v1 = acc[1][r] + biasB[1 * 16 + lo];
            float v2 = acc[2][r] + biasB[2 * 16 + lo];
            float v3 = acc[3][r] + biasB[3 * 16 + lo];
            float mx = fmaxf(fmaxf(v0, v1), fmaxf(v2, v3));
            for (int d = 1; d < 16; d <<= 1) mx = fmaxf(mx, __shfl_xor(mx, d));
            float sm = __expf(v0 - mx) + __expf(v1 - mx) + __expf(v2 - mx) + __expf(v3 - mx);
            for (int d = 1; d < 16; d <<= 1) sm += __shfl_xor(sm, d);
            float lse = mx + __logf(sm);
            if (node < n) {
                outf[(size_t)node * 64 + 0 * 16 + lo] = v0 - lse;
                outf[(size_t)node * 64 + 1 * 16 + lo] = v1 - lse;
                outf[(size_t)node * 64 + 2 * 16 + lo] = v2 - lse;
                outf[(size_t)node * 64 + 3 * 16 + lo] = v3 - lse;
            }
        }
    }
}

// ---------------- launch ----------------

extern "C" void kernel_launch(void* const* d_in, const int* in_sizes, int n_in,
                              void* d_out, int out_size, void* d_ws, size_t ws_size,
                              hipStream_t stream) {
    const float* x  = (const float*)d_in[0];
    const int*   ei = (const int*)d_in[1];   // int32 (JAX x64 disabled demotes int64)
    const float* W1 = (const float*)d_in[2];
    const float* b1 = (const float*)d_in[3];
    const float* W2 = (const float*)d_in[4];
    const float* b2 = (const float*)d_in[5];
    const float* W3 = (const float*)d_in[6];
    const float* b3 = (const float*)d_in[7];
    const float* W4 = (const float*)d_in[8];
    const float* b4 = (const float*)d_in[9];
    float* outp = (float*)d_out;

    const int N = NNODES;
    const int E = NEDGES;
    const int* srcp = ei;
    const int* dstp = ei + E;

    char* w = (char*)d_ws;
    size_t o = 0;
    auto alloc = [&](size_t bytes) { size_t r = o; o = (o + bytes + 255) & ~(size_t)255; return r; };
    size_t cnt_off   = alloc((size_t)N * 4);
    size_t off_off   = alloc((size_t)N * 4);
    size_t dinv_off  = alloc((size_t)N * 4);
    size_t histg_off = alloc((size_t)SCAN_N * 4);
    size_t gscan_off = alloc((size_t)SCAN_N * 4);
    size_t bs_off    = alloc(256 * 4);
    size_t part_off  = alloc((size_t)E * 4);
    size_t csr_off   = alloc((size_t)E * 4);
    size_t hp_off    = alloc((size_t)(N + 1) * 64 * 2);  // +1 zeroed pad row
    size_t abf_off   = alloc((size_t)N * 64 * 2);
    size_t wp1_off   = alloc(128 * 64 * 2);
    size_t wp2_off   = alloc(64 * 64 * 2);
    size_t wp34_off  = alloc(64 * 64 * 2);
    size_t b34_off   = alloc(64 * 4);

    int*            cnt   = (int*)(w + cnt_off);
    int*            off   = (int*)(w + off_off);
    float*          dinv  = (float*)(w + dinv_off);
    int*            histg = (int*)(w + histg_off);
    int*            gscan = (int*)(w + gscan_off);
    int*            bs    = (int*)(w + bs_off);
    unsigned int*   part  = (unsigned int*)(w + part_off);
    int*            csr   = (int*)(w + csr_off);
    unsigned short* hp    = (unsigned short*)(w + hp_off);
    unsigned short* abf   = (unsigned short*)(w + abf_off);
    unsigned short* Wp1   = (unsigned short*)(w + wp1_off);
    unsigned short* Wp2   = (unsigned short*)(w + wp2_off);
    unsigned short* Wp34  = (unsigned short*)(w + wp34_off);
    float*          b34   = (float*)(w + b34_off);

    histprep_kernel<<<PB + 66, 256, 0, stream>>>(dstp, histg, W1, W2, W3, W4, b3, b4,
                                                 Wp1, Wp2, Wp34, b34, hp);
    scan1_kernel<<<SB, 256, 0, stream>>>(histg, gscan, bs, SCAN_N);
    part_kernel<<<PB, 256, 0, stream>>>(srcp, dstp, histg, gscan, bs, part);
    csrgemm_kernel<<<NB, 256, 0, stream>>>(part, gscan, bs, x, Wp1, csr, cnt, off, dinv, hp, N);

    const int ab = (N + ANB - 1) / ANB;   // 1563

    aggfuse_kernel<false><<<ab, 256, 0, stream>>>(hp, csr, off, cnt, dinv, b1, Wp2,
                                                  nullptr, abf, nullptr, N);
    aggfuse_kernel<true><<<ab, 256, 0, stream>>>(abf, csr, off, cnt, dinv, b2, Wp34,
                                                 b34, nullptr, outp, N);
}